// Round 2
// baseline (873.558 us; speedup 1.0000x reference)
//
// Round 5: depth-3 pipelined GEMM (4 LDS buffers, vmcnt(3*NL) counted waits,
// raw s_barrier + compile-fences) + bank-conflict XOR swizzle applied
// both-sides (pre-swizzled global source chunk for linear global_load_lds
// dest, same XOR on ds_read slot). Everything else unchanged from round 4.
#include <hip/hip_runtime.h>

#define D_MODEL 768
#define D_INNER 1536
#define D_XZ    3072
#define D_STATE 16
#define LSEQ    1024
#define NCHUNK  32
#define CLEN    32

typedef float  floatx4 __attribute__((ext_vector_type(4)));
typedef __bf16 bf16x2  __attribute__((ext_vector_type(2)));
typedef __bf16 bf16x8  __attribute__((ext_vector_type(8)));

__device__ __forceinline__ float softplus_f(float x) {
  float e = __expf(-fabsf(x));
  return fmaxf(x, 0.f) + __logf(1.f + e);
}
__device__ __forceinline__ float silu_f(float x) {
  return x / (1.f + __expf(-x));
}
__device__ __forceinline__ void gload_lds16(const void* g, void* l) {
  __builtin_amdgcn_global_load_lds(
      (const __attribute__((address_space(1))) void*)g,
      (__attribute__((address_space(3))) void*)l, 16, 0, 0);
}

// counted vmcnt wait; "n" pastes the immediate; memory clobber pins mem ops
template <int N> __device__ __forceinline__ void waitcnt_vm() {
  asm volatile("s_waitcnt vmcnt(%0)" ::"n"(N) : "memory");
}
// compile-time memory fence: stops ds_read/DMA migration across s_barrier
__device__ __forceinline__ void cfence() { asm volatile("" ::: "memory"); }

// ---------------- fp32 -> bf16 bulk convert (8 elems/thread) ----------------
__global__ __launch_bounds__(256) void k_cvt(const float* __restrict__ src,
                                             __bf16* __restrict__ dst) {
  size_t i = ((size_t)blockIdx.x * 256 + threadIdx.x) * 8;
  float4 a = *(const float4*)(src + i);
  float4 b = *(const float4*)(src + i + 4);
  bf16x8 o;
  o[0] = (__bf16)a.x; o[1] = (__bf16)a.y; o[2] = (__bf16)a.z; o[3] = (__bf16)a.w;
  o[4] = (__bf16)b.x; o[5] = (__bf16)b.y; o[6] = (__bf16)b.z; o[7] = (__bf16)b.w;
  *(bf16x8*)(dst + i) = o;
}

// ---------------- embed gather ----------------
__global__ __launch_bounds__(256) void k_gather(const float* __restrict__ embed,
                                                const int* __restrict__ idx,
                                                float* __restrict__ x) {
  int t = blockIdx.x;
  int tok = idx[t];
  const float* src = embed + (size_t)tok * D_MODEL;
  float* dst = x + (size_t)t * D_MODEL;
  for (int c = threadIdx.x; c < D_MODEL; c += 256) dst[c] = src[c];
}

// ---------------- rmsnorm -> bf16 out (wave per row) ----------------
__global__ __launch_bounds__(256) void k_rmsnorm_bf(const float* __restrict__ x,
                                                    const float* __restrict__ w,
                                                    __bf16* __restrict__ o) {
  int lane = threadIdx.x & 63;
  int row = blockIdx.x * 4 + (threadIdx.x >> 6);
  const float* xr = x + (size_t)row * D_MODEL;
  float2 v[6];
  float ss = 0.f;
#pragma unroll
  for (int i = 0; i < 6; i++) {
    v[i] = *(const float2*)(xr + lane * 2 + i * 128);
    ss += v[i].x * v[i].x + v[i].y * v[i].y;
  }
#pragma unroll
  for (int m = 32; m; m >>= 1) ss += __shfl_xor(ss, m, 64);
  float r = rsqrtf(ss * (1.f / 768.f) + 1e-5f);
  __bf16* orow = o + (size_t)row * D_MODEL;
#pragma unroll
  for (int i = 0; i < 6; i++) {
    float2 wv = *(const float2*)(w + lane * 2 + i * 128);
    bf16x2 p;
    p[0] = (__bf16)(v[i].x * r * wv.x);
    p[1] = (__bf16)(v[i].y * r * wv.y);
    *(bf16x2*)(orow + lane * 2 + i * 128) = p;
  }
}

// ---------------- bf16 NT GEMM, depth-3 pipelined, bank-swizzled ----------------
// C[m,n] = res?[m,n] + sum_k A[m,k]*B[n,k].  A: MxK bf16, B: NxK bf16, C fp32.
// 4 LDS buffers; tile kt+3 issued at step kt; vmcnt(3*NL) leaves 3 K-tiles in
// flight across barriers. LDS 16B-slot swizzle: slot c of row r holds global
// chunk c ^ ((r>>1)&3) (source pre-swizzled since global_load_lds dest is
// linear); ds_read applies the same XOR -> 2-way residual conflicts (free).
template <int TM, int TN>
__global__ __launch_bounds__(256) void k_gemm_bb(const __bf16* __restrict__ A,
                                                 const __bf16* __restrict__ B,
                                                 const float* res, float* __restrict__ C,
                                                 int M, int N, int K, int mTiles) {
  constexpr int MT  = TM / 32;   // m-frags per wave
  constexpr int NTL = TN / 32;   // n-frags per wave
  constexpr int NLA = TM / 64;   // per-thread A gload_lds per K-step
  constexpr int NLB = TN / 64;   // per-thread B gload_lds per K-step
  constexpr int NL  = NLA + NLB;
  __shared__ __attribute__((aligned(16))) __bf16 As[4][TM * 32];
  __shared__ __attribute__((aligned(16))) __bf16 Bs[4][TN * 32];
  const int tid = threadIdx.x;
  const int lane = tid & 63, wave = tid >> 6;
  const int fr = lane & 15, q = lane >> 4;

  int id = blockIdx.x;
  int per = gridDim.x >> 3;                       // grid % 8 == 0 at all call sites
  int v = (id & 7) * per + (id >> 3);             // XCD-contiguous mapping
  int nt = v / mTiles, mt_ = v % mTiles;
  const int Mblk = mt_ * TM, Nblk = nt * TN;
  const int wm = (wave & 1) * (TM / 2), wn = (wave >> 1) * (TN / 2);

  const int row_s = tid >> 2;                     // 0..63
  const int cs = ((tid & 3) ^ ((row_s >> 1) & 3)) * 8;  // swizzled source chunk
  const __bf16* Ag = A + (size_t)(Mblk + row_s) * K + cs;
  const __bf16* Bg = B + (size_t)(Nblk + row_s) * K + cs;

  floatx4 acc[MT][NTL];
#pragma unroll
  for (int i = 0; i < MT; i++)
#pragma unroll
    for (int j = 0; j < NTL; j++) {
      floatx4 z = {0.f, 0.f, 0.f, 0.f};
      acc[i][j] = z;
    }

  const int KT = K >> 5;   // >= 24 at all call sites

#define STAGE_T(t)                                                            \
  do {                                                                        \
    const int _b = (t) & 3;                                                   \
    const int _k0 = (t) << 5;                                                 \
    _Pragma("unroll") for (int i = 0; i < NLA; i++)                           \
        gload_lds16(Ag + (size_t)(64 * i) * K + _k0,                          \
                    &As[_b][tid * 8 + i * 2048]);                             \
    _Pragma("unroll") for (int i = 0; i < NLB; i++)                           \
        gload_lds16(Bg + (size_t)(64 * i) * K + _k0,                          \
                    &Bs[_b][tid * 8 + i * 2048]);                             \
  } while (0)

#define STEP_T(kt, WN)                                                        \
  do {                                                                        \
    const int _cur = (kt) & 3;                                                \
    waitcnt_vm<WN>();                                                         \
    __builtin_amdgcn_s_barrier();  /* all waves' tile-kt DMA landed */        \
    cfence();                                                                 \
    bf16x8 af[MT], bfr[NTL];                                                  \
    _Pragma("unroll") for (int mt = 0; mt < MT; mt++) {                       \
      const int R = wm + mt * 16 + fr;                                        \
      af[mt] = *(const bf16x8*)&As[_cur][R * 32 + ((q ^ ((R >> 1) & 3)) << 3)]; \
    }                                                                         \
    _Pragma("unroll") for (int ntl = 0; ntl < NTL; ntl++) {                   \
      const int R = wn + ntl * 16 + fr;                                       \
      bfr[ntl] = *(const bf16x8*)&Bs[_cur][R * 32 + ((q ^ ((R >> 1) & 3)) << 3)]; \
    }                                                                         \
    _Pragma("unroll") for (int mt = 0; mt < MT; mt++)                         \
      _Pragma("unroll") for (int ntl = 0; ntl < NTL; ntl++)                   \
        acc[mt][ntl] = __builtin_amdgcn_mfma_f32_16x16x32_bf16(               \
            af[mt], bfr[ntl], acc[mt][ntl], 0, 0, 0);                         \
    cfence();                                                                 \
    __builtin_amdgcn_s_barrier();  /* buffer free for overwrite */            \
    cfence();                                                                 \
  } while (0)

  // prologue: stage K-tiles 0..2 into buffers 0..2
  STAGE_T(0);
  STAGE_T(1);
  STAGE_T(2);

  int kt = 0;
  for (; kt < KT - 3; ++kt) {
    STAGE_T(kt + 3);          // into buf (kt+3)&3 = (kt-1)&3, consumed last step
    STEP_T(kt, 3 * NL);       // drain only tile kt; 3 tiles stay in flight
  }
  STEP_T(kt, 2 * NL); ++kt;
  STEP_T(kt, 1 * NL); ++kt;
  STEP_T(kt, 0);

#undef STAGE_T
#undef STEP_T

#pragma unroll
  for (int mt = 0; mt < MT; mt++)
#pragma unroll
    for (int ntl = 0; ntl < NTL; ntl++) {
      int r = Mblk + wm + mt * 16 + (lane >> 4) * 4;
      int c = Nblk + wn + ntl * 16 + fr;
#pragma unroll
      for (int i = 0; i < 4; i++) {
        size_t o = (size_t)(r + i) * N + c;
        float vv = acc[mt][ntl][i];
        if (res) vv += res[o];
        C[o] = vv;
      }
    }
}

// ---------------- fused conv(k=4)+bias+silu -> xc, xp = xc @ Wx^T ----------------
__global__ __launch_bounds__(256) void k_xpconv(const float* __restrict__ xz,
                                                const float* __restrict__ cw4,
                                                const float* __restrict__ cb,
                                                const float* __restrict__ Wx,
                                                float* __restrict__ xc,
                                                float* __restrict__ xp) {
  __shared__ float red[4][33];
  int t = blockIdx.x;
  int wave = threadIdx.x >> 6, lane = threadIdx.x & 63;
  float acc[33];
#pragma unroll
  for (int j = 0; j < 33; j++) acc[j] = 0.f;
  for (int ii = 0; ii < 6; ii++) {
    int k = wave * 384 + ii * 64 + lane;
    float4 w = *(const float4*)(cw4 + (size_t)k * 4);
    float wv[4] = {w.x, w.y, w.z, w.w};
    float vv = cb[k];
#pragma unroll
    for (int jj = 0; jj < 4; jj++) {
      int ts = t - 3 + jj;  // block-uniform branch
      if (ts >= 0) vv += wv[jj] * xz[(size_t)ts * D_XZ + k];
    }
    float xcv = silu_f(vv);
    xc[(size_t)t * D_INNER + k] = xcv;
#pragma unroll
    for (int j = 0; j < 33; j++) acc[j] += xcv * Wx[(size_t)j * D_INNER + k];
  }
#pragma unroll
  for (int j = 0; j < 33; j++) {
    float s = acc[j];
#pragma unroll
    for (int m = 32; m; m >>= 1) s += __shfl_xor(s, m, 64);
    if (lane == j) red[wave][j] = s;
  }
  __syncthreads();
  int j = threadIdx.x;
  if (j < 33) xp[(size_t)t * 33 + j] = red[0][j] + red[1][j] + red[2][j] + red[3][j];
}

// ---------------- scan phase 1 ----------------
__global__ __launch_bounds__(256) void k_scan1(const float* __restrict__ xp,
                                               const float* __restrict__ xc,
                                               const float* __restrict__ dtw,
                                               const float* __restrict__ dtb,
                                               const float* __restrict__ Alog,
                                               float* __restrict__ hend,
                                               float* __restrict__ Pp) {
  __shared__ float sxp[CLEN * 33];
  int c = blockIdx.x;
  int d = blockIdx.y * 256 + threadIdx.x;
  for (int i = threadIdx.x; i < CLEN * 33; i += 256) sxp[i] = xp[(size_t)c * CLEN * 33 + i];
  __syncthreads();
  float Av[16];
#pragma unroll
  for (int n = 0; n < 16; n++) Av[n] = -__expf(Alog[(size_t)d * 16 + n]);
  float w_ = dtw[d], b_ = dtb[d];
  float h[16], P[16];
#pragma unroll
  for (int n = 0; n < 16; n++) { h[n] = 0.f; P[n] = 1.f; }
  const float* xcc = xc + (size_t)(c * CLEN) * D_INNER + d;
  for (int tl = 0; tl < CLEN; tl++) {
    float dtr = sxp[tl * 33];
    float xv = xcc[(size_t)tl * D_INNER];
    float dt = softplus_f(dtr * w_ + b_);
    float sx = dt * xv;
#pragma unroll
    for (int n = 0; n < 16; n++) {
      float dA = __expf(dt * Av[n]);
      h[n] = dA * h[n] + sx * sxp[tl * 33 + 1 + n];
      P[n] *= dA;
    }
  }
  size_t o = ((size_t)c * D_INNER + d) * 16;
#pragma unroll
  for (int n = 0; n < 16; n++) { hend[o + n] = h[n]; Pp[o + n] = P[n]; }
}

// ---------------- scan phase 2: inline chunk-prefix + rescan ----------------
__global__ __launch_bounds__(256) void k_scan2(const float* __restrict__ xp,
                                               const float* __restrict__ xc,
                                               const float* __restrict__ xz,
                                               const float* __restrict__ dtw,
                                               const float* __restrict__ dtb,
                                               const float* __restrict__ Alog,
                                               const float* __restrict__ Dp,
                                               const float* __restrict__ hend,
                                               const float* __restrict__ Pp,
                                               __bf16* __restrict__ g) {
  __shared__ float sxp[CLEN * 33];
  int c = blockIdx.x;
  int d = blockIdx.y * 256 + threadIdx.x;
  for (int i = threadIdx.x; i < CLEN * 33; i += 256) sxp[i] = xp[(size_t)c * CLEN * 33 + i];
  __syncthreads();
  float Av[16];
#pragma unroll
  for (int n = 0; n < 16; n++) Av[n] = -__expf(Alog[(size_t)d * 16 + n]);
  float w_ = dtw[d], b_ = dtb[d], Dv = Dp[d];
  // h0 for this chunk = sequential combine of chunks < c (same FP order as k_comb)
  float h[16];
#pragma unroll
  for (int n = 0; n < 16; n++) h[n] = 0.f;
  for (int c2 = 0; c2 < c; c2++) {
    size_t o = ((size_t)c2 * D_INNER + d) * 16;
#pragma unroll
    for (int n4 = 0; n4 < 4; n4++) {
      float4 hv = *(const float4*)(hend + o + n4 * 4);
      float4 pv = *(const float4*)(Pp + o + n4 * 4);
      h[n4 * 4 + 0] = pv.x * h[n4 * 4 + 0] + hv.x;
      h[n4 * 4 + 1] = pv.y * h[n4 * 4 + 1] + hv.y;
      h[n4 * 4 + 2] = pv.z * h[n4 * 4 + 2] + hv.z;
      h[n4 * 4 + 3] = pv.w * h[n4 * 4 + 3] + hv.w;
    }
  }
  for (int tl = 0; tl < CLEN; tl++) {
    int t = c * CLEN + tl;
    float dtr = sxp[tl * 33];
    float xv = xc[(size_t)t * D_INNER + d];
    float dt = softplus_f(dtr * w_ + b_);
    float sx = dt * xv;
    float y = 0.f;
#pragma unroll
    for (int n = 0; n < 16; n++) {
      float dA = __expf(dt * Av[n]);
      h[n] = dA * h[n] + sx * sxp[tl * 33 + 1 + n];
      y += h[n] * sxp[tl * 33 + 17 + n];
    }
    float z = xz[(size_t)t * D_XZ + D_INNER + d];
    g[(size_t)t * D_INNER + d] = (__bf16)((y + xv * Dv) * silu_f(z));
  }
}

extern "C" void kernel_launch(void* const* d_in, const int* in_sizes, int n_in,
                              void* d_out, int out_size, void* d_ws, size_t ws_size,
                              hipStream_t stream) {
  const int*   idx     = (const int*)d_in[0];
  const float* embed   = (const float*)d_in[1];
  const float* norm_w  = (const float*)d_in[2];
  const float* W_in    = (const float*)d_in[3];
  const float* conv_w  = (const float*)d_in[4];
  const float* conv_b  = (const float*)d_in[5];
  const float* W_x     = (const float*)d_in[6];
  const float* dt_w    = (const float*)d_in[7];
  const float* dt_b    = (const float*)d_in[8];
  const float* A_log   = (const float*)d_in[9];
  const float* Dp      = (const float*)d_in[10];
  const float* out_w   = (const float*)d_in[11];
  const float* norm_fw = (const float*)d_in[12];
  float* out = (float*)d_out;

  // ---- workspace layout (pool region re-used for bf16 embed at the end) ----
  float*  x    = (float*)d_ws;                     // 786432 f
  __bf16* xnb  = (__bf16*)(x + 786432);            // 786432 bf
  float*  xp   = (float*)(xnb + 786432);           // 33792 f
  float*  Pp   = xp + 33792;                       // 786432 f
  __bf16* gbf  = (__bf16*)(Pp + 786432);           // 1572864 bf
  __bf16* pool = gbf + 1572864;                    // pool: ~50.3 MB
  __bf16* W_in_bf  = pool;                         // 9437184 bf
  __bf16* out_w_bf = pool + 9437184;               // 4718592 bf
  float*  xz   = (float*)(out_w_bf + 4718592);     // 3145728 f
  float*  xc   = xz + 3145728;                     // 1572864 f
  float*  hend = xc + 1572864;                     // 786432 f
  __bf16* emb_bf = pool;                           // 24576000 bf (aliases pool AFTER layers)

  // weight conversions (embed deferred until pool is dead)
  k_cvt<<<4608, 256, 0, stream>>>(W_in, W_in_bf);      // 9,437,184 elems
  k_cvt<<<2304, 256, 0, stream>>>(out_w, out_w_bf);    // 4,718,592 elems

  k_gather<<<1024, 256, 0, stream>>>(embed, idx, x);

  for (int l = 0; l < 4; l++) {
    k_rmsnorm_bf<<<256, 256, 0, stream>>>(x, norm_w + (size_t)l * D_MODEL, xnb);
    // xz = xn @ W_in^T : M=1024 N=3072 K=768 -> TM=64,TN=128: 24 nt x 16 mt = 384 blocks
    k_gemm_bb<64, 128><<<384, 256, 0, stream>>>(xnb, W_in_bf + (size_t)l * D_XZ * D_MODEL,
                                                nullptr, xz, 1024, D_XZ, D_MODEL, 16);
    k_xpconv<<<1024, 256, 0, stream>>>(xz, conv_w + (size_t)l * D_INNER * 4,
                                       conv_b + (size_t)l * D_INNER,
                                       W_x + (size_t)l * 33 * D_INNER, xc, xp);
    k_scan1<<<dim3(NCHUNK, 6), 256, 0, stream>>>(xp, xc, dt_w + (size_t)l * D_INNER,
                                                 dt_b + (size_t)l * D_INNER,
                                                 A_log + (size_t)l * D_INNER * 16, hend, Pp);
    k_scan2<<<dim3(NCHUNK, 6), 256, 0, stream>>>(xp, xc, xz, dt_w + (size_t)l * D_INNER,
                                                 dt_b + (size_t)l * D_INNER,
                                                 A_log + (size_t)l * D_INNER * 16,
                                                 Dp + (size_t)l * D_INNER, hend, Pp, gbf);
    // x = x + g @ out_w^T : M=1024 N=768 K=1536 -> TM=64,TN=64: 12 nt x 16 mt = 192 blocks
    k_gemm_bb<64, 64><<<192, 256, 0, stream>>>(gbf, out_w_bf + (size_t)l * D_MODEL * D_INNER,
                                               x, x, 1024, D_MODEL, D_INNER, 16);
  }

  // pool (W_in_bf/out_w_bf/xz/xc/hend) is dead now -> convert embed into it
  k_cvt<<<12000, 256, 0, stream>>>(embed, emb_bf);     // 24,576,000 elems
  k_rmsnorm_bf<<<256, 256, 0, stream>>>(x, norm_fw, xnb);
  // logits = xn @ embed^T : M=1024 N=32000 K=768 -> 250 nt x 8 mt = 2000 blocks
  k_gemm_bb<128, 128><<<2000, 256, 0, stream>>>(xnb, emb_bf, nullptr, out,
                                                1024, 32000, D_MODEL, 8);
}

// Round 3
// 823.629 us; speedup vs baseline: 1.0606x; 1.0606x over previous
//
// Round 6: balance pipeline depth x residency: 3 LDS buffers (48KB for 128^2
// -> 3 blocks/CU; 24KB for 64^2 -> 6), depth-2 counted vmcnt (2 K-tiles in
// flight across barriers), swizzle kept (round-5: conflicts 6.1M -> 0).
// out-GEMM parallelized via deterministic split-K=4 (192 -> 768 blocks,
// partials in dead xz region + k_redK adds residual). W_in GEMM -> <64,64>
// (768 blocks). Logits unchanged shape <128,128> x 2000 blocks.
#include <hip/hip_runtime.h>

#define D_MODEL 768
#define D_INNER 1536
#define D_XZ    3072
#define D_STATE 16
#define LSEQ    1024
#define NCHUNK  32
#define CLEN    32

typedef float  floatx4 __attribute__((ext_vector_type(4)));
typedef __bf16 bf16x2  __attribute__((ext_vector_type(2)));
typedef __bf16 bf16x8  __attribute__((ext_vector_type(8)));

__device__ __forceinline__ float softplus_f(float x) {
  float e = __expf(-fabsf(x));
  return fmaxf(x, 0.f) + __logf(1.f + e);
}
__device__ __forceinline__ float silu_f(float x) {
  return x / (1.f + __expf(-x));
}
__device__ __forceinline__ void gload_lds16(const void* g, void* l) {
  __builtin_amdgcn_global_load_lds(
      (const __attribute__((address_space(1))) void*)g,
      (__attribute__((address_space(3))) void*)l, 16, 0, 0);
}

// counted vmcnt wait; "n" pastes the immediate; memory clobber pins mem ops
template <int N> __device__ __forceinline__ void waitcnt_vm() {
  asm volatile("s_waitcnt vmcnt(%0)" ::"n"(N) : "memory");
}
__device__ __forceinline__ void cfence() { asm volatile("" ::: "memory"); }

// ---------------- fp32 -> bf16 bulk convert (8 elems/thread) ----------------
__global__ __launch_bounds__(256) void k_cvt(const float* __restrict__ src,
                                             __bf16* __restrict__ dst) {
  size_t i = ((size_t)blockIdx.x * 256 + threadIdx.x) * 8;
  float4 a = *(const float4*)(src + i);
  float4 b = *(const float4*)(src + i + 4);
  bf16x8 o;
  o[0] = (__bf16)a.x; o[1] = (__bf16)a.y; o[2] = (__bf16)a.z; o[3] = (__bf16)a.w;
  o[4] = (__bf16)b.x; o[5] = (__bf16)b.y; o[6] = (__bf16)b.z; o[7] = (__bf16)b.w;
  *(bf16x8*)(dst + i) = o;
}

// ---------------- embed gather ----------------
__global__ __launch_bounds__(256) void k_gather(const float* __restrict__ embed,
                                                const int* __restrict__ idx,
                                                float* __restrict__ x) {
  int t = blockIdx.x;
  int tok = idx[t];
  const float* src = embed + (size_t)tok * D_MODEL;
  float* dst = x + (size_t)t * D_MODEL;
  for (int c = threadIdx.x; c < D_MODEL; c += 256) dst[c] = src[c];
}

// ---------------- rmsnorm -> bf16 out (wave per row) ----------------
__global__ __launch_bounds__(256) void k_rmsnorm_bf(const float* __restrict__ x,
                                                    const float* __restrict__ w,
                                                    __bf16* __restrict__ o) {
  int lane = threadIdx.x & 63;
  int row = blockIdx.x * 4 + (threadIdx.x >> 6);
  const float* xr = x + (size_t)row * D_MODEL;
  float2 v[6];
  float ss = 0.f;
#pragma unroll
  for (int i = 0; i < 6; i++) {
    v[i] = *(const float2*)(xr + lane * 2 + i * 128);
    ss += v[i].x * v[i].x + v[i].y * v[i].y;
  }
#pragma unroll
  for (int m = 32; m; m >>= 1) ss += __shfl_xor(ss, m, 64);
  float r = rsqrtf(ss * (1.f / 768.f) + 1e-5f);
  __bf16* orow = o + (size_t)row * D_MODEL;
#pragma unroll
  for (int i = 0; i < 6; i++) {
    float2 wv = *(const float2*)(w + lane * 2 + i * 128);
    bf16x2 p;
    p[0] = (__bf16)(v[i].x * r * wv.x);
    p[1] = (__bf16)(v[i].y * r * wv.y);
    *(bf16x2*)(orow + lane * 2 + i * 128) = p;
  }
}

// ---------------- bf16 NT GEMM: 3-buffer depth-2 pipeline, swizzled ----------------
// C[m,n] = res?[m,n] + sum_k A[m,k]*B[n,k].  A: MxK bf16, B: NxK bf16, C fp32.
// SK>1: split-K; slice s computes cols [s*K/SK, (s+1)*K/SK) into partial
// C + s*M*N (res must be nullptr; reduce adds residual afterwards).
template <int TM, int TN, int SK>
__global__ __launch_bounds__(256, 3) void k_gemm_bb(const __bf16* __restrict__ A,
                                                    const __bf16* __restrict__ B,
                                                    const float* res, float* __restrict__ C,
                                                    int M, int N, int K, int mTiles) {
  constexpr int MT  = TM / 32;   // m-frags per wave
  constexpr int NTL = TN / 32;   // n-frags per wave
  constexpr int NLA = TM / 64;   // per-thread A gload_lds per K-step
  constexpr int NLB = TN / 64;   // per-thread B gload_lds per K-step
  constexpr int NL  = NLA + NLB;
  __shared__ __attribute__((aligned(16))) __bf16 As[3][TM * 32];
  __shared__ __attribute__((aligned(16))) __bf16 Bs[3][TN * 32];
  const int tid = threadIdx.x;
  const int lane = tid & 63, wave = tid >> 6;
  const int fr = lane & 15, q = lane >> 4;

  int id = blockIdx.x;
  int per = gridDim.x >> 3;                       // grid % 8 == 0 at all call sites
  int v = (id & 7) * per + (id >> 3);             // XCD-contiguous mapping
  int s = 0, rr = v;
  if (SK > 1) { int perS = gridDim.x / SK; s = v / perS; rr = v % perS; }
  int nt = rr / mTiles, mt_ = rr % mTiles;
  const int Mblk = mt_ * TM, Nblk = nt * TN;
  const int wm = (wave & 1) * (TM / 2), wn = (wave >> 1) * (TN / 2);
  const int Ks = K / SK;

  const int row_s = tid >> 2;                     // 0..63
  const int cs = ((tid & 3) ^ ((row_s >> 1) & 3)) * 8;  // swizzled source chunk
  const __bf16* Ag = A + (size_t)(Mblk + row_s) * K + (size_t)s * Ks + cs;
  const __bf16* Bg = B + (size_t)(Nblk + row_s) * K + (size_t)s * Ks + cs;
  if (SK > 1) C += (size_t)s * M * N;

  floatx4 acc[MT][NTL];
#pragma unroll
  for (int i = 0; i < MT; i++)
#pragma unroll
    for (int j = 0; j < NTL; j++) {
      floatx4 z = {0.f, 0.f, 0.f, 0.f};
      acc[i][j] = z;
    }

  const int KT = Ks >> 5;   // >= 12 at all call sites

#define STAGE_T(t, b)                                                         \
  do {                                                                        \
    const int _k0 = (t) << 5;                                                 \
    _Pragma("unroll") for (int i = 0; i < NLA; i++)                           \
        gload_lds16(Ag + (size_t)(64 * i) * K + _k0,                          \
                    &As[b][tid * 8 + i * 2048]);                              \
    _Pragma("unroll") for (int i = 0; i < NLB; i++)                           \
        gload_lds16(Bg + (size_t)(64 * i) * K + _k0,                          \
                    &Bs[b][tid * 8 + i * 2048]);                              \
  } while (0)

#define STEP_T(b, WN)                                                         \
  do {                                                                        \
    waitcnt_vm<WN>();                                                         \
    __builtin_amdgcn_s_barrier();  /* all waves' current-tile DMA landed */   \
    cfence();                                                                 \
    bf16x8 af[MT], bfr[NTL];                                                  \
    _Pragma("unroll") for (int mt = 0; mt < MT; mt++) {                       \
      const int R = wm + mt * 16 + fr;                                        \
      af[mt] = *(const bf16x8*)&As[b][R * 32 + ((q ^ ((R >> 1) & 3)) << 3)];  \
    }                                                                         \
    _Pragma("unroll") for (int ntl = 0; ntl < NTL; ntl++) {                   \
      const int R = wn + ntl * 16 + fr;                                       \
      bfr[ntl] = *(const bf16x8*)&Bs[b][R * 32 + ((q ^ ((R >> 1) & 3)) << 3)]; \
    }                                                                         \
    _Pragma("unroll") for (int mt = 0; mt < MT; mt++)                         \
      _Pragma("unroll") for (int ntl = 0; ntl < NTL; ntl++)                   \
        acc[mt][ntl] = __builtin_amdgcn_mfma_f32_16x16x32_bf16(               \
            af[mt], bfr[ntl], acc[mt][ntl], 0, 0, 0);                         \
    cfence();                                                                 \
    __builtin_amdgcn_s_barrier();  /* buffer free for overwrite */            \
    cfence();                                                                 \
  } while (0)

  // prologue: stage K-tiles 0,1 into buffers 0,1
  STAGE_T(0, 0);
  STAGE_T(1, 1);

  int bcur = 0, bpre = 2;  // bpre = buffer receiving tile kt+2
  for (int kt = 0; kt < KT - 2; ++kt) {
    STAGE_T(kt + 2, bpre);       // overwrites buffer consumed at step kt-1
    STEP_T(bcur, 2 * NL);        // drain tile kt only; 2 tiles stay in flight
    bcur = (bcur == 2) ? 0 : bcur + 1;
    bpre = (bpre == 2) ? 0 : bpre + 1;
  }
  STEP_T(bcur, NL);
  bcur = (bcur == 2) ? 0 : bcur + 1;
  STEP_T(bcur, 0);

#undef STAGE_T
#undef STEP_T

#pragma unroll
  for (int mt = 0; mt < MT; mt++)
#pragma unroll
    for (int ntl = 0; ntl < NTL; ntl++) {
      int r = Mblk + wm + mt * 16 + q * 4;
      int c = Nblk + wn + ntl * 16 + fr;
#pragma unroll
      for (int i = 0; i < 4; i++) {
        size_t o = (size_t)(r + i) * N + c;
        float vv = acc[mt][ntl][i];
        if (res) vv += res[o];
        C[o] = vv;
      }
    }
}

// ---------------- split-K reduce: x += p0+p1+p2+p3 ----------------
__global__ __launch_bounds__(256) void k_redK(const float* __restrict__ p,
                                              float* __restrict__ x) {
  size_t i = ((size_t)blockIdx.x * 256 + threadIdx.x) * 4;
  float4 a  = *(float4*)(x + i);
  float4 p0 = *(const float4*)(p + i);
  float4 p1 = *(const float4*)(p + 786432 + i);
  float4 p2 = *(const float4*)(p + 2 * 786432 + i);
  float4 p3 = *(const float4*)(p + 3 * 786432 + i);
  a.x += ((p0.x + p1.x) + p2.x) + p3.x;
  a.y += ((p0.y + p1.y) + p2.y) + p3.y;
  a.z += ((p0.z + p1.z) + p2.z) + p3.z;
  a.w += ((p0.w + p1.w) + p2.w) + p3.w;
  *(float4*)(x + i) = a;
}

// ---------------- fused conv(k=4)+bias+silu -> xc, xp = xc @ Wx^T ----------------
__global__ __launch_bounds__(256) void k_xpconv(const float* __restrict__ xz,
                                                const float* __restrict__ cw4,
                                                const float* __restrict__ cb,
                                                const float* __restrict__ Wx,
                                                float* __restrict__ xc,
                                                float* __restrict__ xp) {
  __shared__ float red[4][33];
  int t = blockIdx.x;
  int wave = threadIdx.x >> 6, lane = threadIdx.x & 63;
  float acc[33];
#pragma unroll
  for (int j = 0; j < 33; j++) acc[j] = 0.f;
  for (int ii = 0; ii < 6; ii++) {
    int k = wave * 384 + ii * 64 + lane;
    float4 w = *(const float4*)(cw4 + (size_t)k * 4);
    float wv[4] = {w.x, w.y, w.z, w.w};
    float vv = cb[k];
#pragma unroll
    for (int jj = 0; jj < 4; jj++) {
      int ts = t - 3 + jj;  // block-uniform branch
      if (ts >= 0) vv += wv[jj] * xz[(size_t)ts * D_XZ + k];
    }
    float xcv = silu_f(vv);
    xc[(size_t)t * D_INNER + k] = xcv;
#pragma unroll
    for (int j = 0; j < 33; j++) acc[j] += xcv * Wx[(size_t)j * D_INNER + k];
  }
#pragma unroll
  for (int j = 0; j < 33; j++) {
    float s = acc[j];
#pragma unroll
    for (int m = 32; m; m >>= 1) s += __shfl_xor(s, m, 64);
    if (lane == j) red[wave][j] = s;
  }
  __syncthreads();
  int j = threadIdx.x;
  if (j < 33) xp[(size_t)t * 33 + j] = red[0][j] + red[1][j] + red[2][j] + red[3][j];
}

// ---------------- scan phase 1 ----------------
__global__ __launch_bounds__(256) void k_scan1(const float* __restrict__ xp,
                                               const float* __restrict__ xc,
                                               const float* __restrict__ dtw,
                                               const float* __restrict__ dtb,
                                               const float* __restrict__ Alog,
                                               float* __restrict__ hend,
                                               float* __restrict__ Pp) {
  __shared__ float sxp[CLEN * 33];
  int c = blockIdx.x;
  int d = blockIdx.y * 256 + threadIdx.x;
  for (int i = threadIdx.x; i < CLEN * 33; i += 256) sxp[i] = xp[(size_t)c * CLEN * 33 + i];
  __syncthreads();
  float Av[16];
#pragma unroll
  for (int n = 0; n < 16; n++) Av[n] = -__expf(Alog[(size_t)d * 16 + n]);
  float w_ = dtw[d], b_ = dtb[d];
  float h[16], P[16];
#pragma unroll
  for (int n = 0; n < 16; n++) { h[n] = 0.f; P[n] = 1.f; }
  const float* xcc = xc + (size_t)(c * CLEN) * D_INNER + d;
  for (int tl = 0; tl < CLEN; tl++) {
    float dtr = sxp[tl * 33];
    float xv = xcc[(size_t)tl * D_INNER];
    float dt = softplus_f(dtr * w_ + b_);
    float sx = dt * xv;
#pragma unroll
    for (int n = 0; n < 16; n++) {
      float dA = __expf(dt * Av[n]);
      h[n] = dA * h[n] + sx * sxp[tl * 33 + 1 + n];
      P[n] *= dA;
    }
  }
  size_t o = ((size_t)c * D_INNER + d) * 16;
#pragma unroll
  for (int n = 0; n < 16; n++) { hend[o + n] = h[n]; Pp[o + n] = P[n]; }
}

// ---------------- scan phase 2: inline chunk-prefix + rescan ----------------
__global__ __launch_bounds__(256) void k_scan2(const float* __restrict__ xp,
                                               const float* __restrict__ xc,
                                               const float* __restrict__ xz,
                                               const float* __restrict__ dtw,
                                               const float* __restrict__ dtb,
                                               const float* __restrict__ Alog,
                                               const float* __restrict__ Dp,
                                               const float* __restrict__ hend,
                                               const float* __restrict__ Pp,
                                               __bf16* __restrict__ g) {
  __shared__ float sxp[CLEN * 33];
  int c = blockIdx.x;
  int d = blockIdx.y * 256 + threadIdx.x;
  for (int i = threadIdx.x; i < CLEN * 33; i += 256) sxp[i] = xp[(size_t)c * CLEN * 33 + i];
  __syncthreads();
  float Av[16];
#pragma unroll
  for (int n = 0; n < 16; n++) Av[n] = -__expf(Alog[(size_t)d * 16 + n]);
  float w_ = dtw[d], b_ = dtb[d], Dv = Dp[d];
  float h[16];
#pragma unroll
  for (int n = 0; n < 16; n++) h[n] = 0.f;
  for (int c2 = 0; c2 < c; c2++) {
    size_t o = ((size_t)c2 * D_INNER + d) * 16;
#pragma unroll
    for (int n4 = 0; n4 < 4; n4++) {
      float4 hv = *(const float4*)(hend + o + n4 * 4);
      float4 pv = *(const float4*)(Pp + o + n4 * 4);
      h[n4 * 4 + 0] = pv.x * h[n4 * 4 + 0] + hv.x;
      h[n4 * 4 + 1] = pv.y * h[n4 * 4 + 1] + hv.y;
      h[n4 * 4 + 2] = pv.z * h[n4 * 4 + 2] + hv.z;
      h[n4 * 4 + 3] = pv.w * h[n4 * 4 + 3] + hv.w;
    }
  }
  for (int tl = 0; tl < CLEN; tl++) {
    int t = c * CLEN + tl;
    float dtr = sxp[tl * 33];
    float xv = xc[(size_t)t * D_INNER + d];
    float dt = softplus_f(dtr * w_ + b_);
    float sx = dt * xv;
    float y = 0.f;
#pragma unroll
    for (int n = 0; n < 16; n++) {
      float dA = __expf(dt * Av[n]);
      h[n] = dA * h[n] + sx * sxp[tl * 33 + 1 + n];
      y += h[n] * sxp[tl * 33 + 17 + n];
    }
    float z = xz[(size_t)t * D_XZ + D_INNER + d];
    g[(size_t)t * D_INNER + d] = (__bf16)((y + xv * Dv) * silu_f(z));
  }
}

extern "C" void kernel_launch(void* const* d_in, const int* in_sizes, int n_in,
                              void* d_out, int out_size, void* d_ws, size_t ws_size,
                              hipStream_t stream) {
  const int*   idx     = (const int*)d_in[0];
  const float* embed   = (const float*)d_in[1];
  const float* norm_w  = (const float*)d_in[2];
  const float* W_in    = (const float*)d_in[3];
  const float* conv_w  = (const float*)d_in[4];
  const float* conv_b  = (const float*)d_in[5];
  const float* W_x     = (const float*)d_in[6];
  const float* dt_w    = (const float*)d_in[7];
  const float* dt_b    = (const float*)d_in[8];
  const float* A_log   = (const float*)d_in[9];
  const float* Dp      = (const float*)d_in[10];
  const float* out_w   = (const float*)d_in[11];
  const float* norm_fw = (const float*)d_in[12];
  float* out = (float*)d_out;

  // ---- workspace layout (pool region re-used for bf16 embed at the end) ----
  float*  x    = (float*)d_ws;                     // 786432 f
  __bf16* xnb  = (__bf16*)(x + 786432);            // 786432 bf
  float*  xp   = (float*)(xnb + 786432);           // 33792 f
  float*  Pp   = xp + 33792;                       // 786432 f
  __bf16* gbf  = (__bf16*)(Pp + 786432);           // 1572864 bf
  __bf16* pool = gbf + 1572864;                    // pool: ~50.3 MB
  __bf16* W_in_bf  = pool;                         // 9437184 bf
  __bf16* out_w_bf = pool + 9437184;               // 4718592 bf
  float*  xz   = (float*)(out_w_bf + 4718592);     // 3145728 f (also split-K partials)
  float*  xc   = xz + 3145728;                     // 1572864 f
  float*  hend = xc + 1572864;                     // 786432 f
  __bf16* emb_bf = pool;                           // 24576000 bf (aliases pool AFTER layers)

  // weight conversions (embed deferred until pool is dead)
  k_cvt<<<4608, 256, 0, stream>>>(W_in, W_in_bf);      // 9,437,184 elems
  k_cvt<<<2304, 256, 0, stream>>>(out_w, out_w_bf);    // 4,718,592 elems

  k_gather<<<1024, 256, 0, stream>>>(embed, idx, x);

  for (int l = 0; l < 4; l++) {
    k_rmsnorm_bf<<<256, 256, 0, stream>>>(x, norm_w + (size_t)l * D_MODEL, xnb);
    // xz = xn @ W_in^T : M=1024 N=3072 K=768 -> <64,64>: 48 nt x 16 mt = 768 blocks
    k_gemm_bb<64, 64, 1><<<768, 256, 0, stream>>>(xnb, W_in_bf + (size_t)l * D_XZ * D_MODEL,
                                                  nullptr, xz, 1024, D_XZ, D_MODEL, 16);
    k_xpconv<<<1024, 256, 0, stream>>>(xz, conv_w + (size_t)l * D_INNER * 4,
                                       conv_b + (size_t)l * D_INNER,
                                       W_x + (size_t)l * 33 * D_INNER, xc, xp);
    k_scan1<<<dim3(NCHUNK, 6), 256, 0, stream>>>(xp, xc, dt_w + (size_t)l * D_INNER,
                                                 dt_b + (size_t)l * D_INNER,
                                                 A_log + (size_t)l * D_INNER * 16, hend, Pp);
    k_scan2<<<dim3(NCHUNK, 6), 256, 0, stream>>>(xp, xc, xz, dt_w + (size_t)l * D_INNER,
                                                 dt_b + (size_t)l * D_INNER,
                                                 A_log + (size_t)l * D_INNER * 16,
                                                 Dp + (size_t)l * D_INNER, hend, Pp, gbf);
    // out-proj split-K=4: partials into xz (dead after scan2), 12 nt x 16 mt x 4 s = 768 blocks
    k_gemm_bb<64, 64, 4><<<768, 256, 0, stream>>>(gbf, out_w_bf + (size_t)l * D_MODEL * D_INNER,
                                                  nullptr, xz, 1024, D_MODEL, D_INNER, 16);
    // x += p0+p1+p2+p3
    k_redK<<<768, 256, 0, stream>>>(xz, x);
  }

  // pool (W_in_bf/out_w_bf/xz/xc/hend) is dead now -> convert embed into it
  k_cvt<<<12000, 256, 0, stream>>>(embed, emb_bf);     // 24,576,000 elems
  k_rmsnorm_bf<<<256, 256, 0, stream>>>(x, norm_fw, xnb);
  // logits = xn @ embed^T : M=1024 N=32000 K=768 -> 250 nt x 8 mt = 2000 blocks
  k_gemm_bb<128, 128, 1><<<2000, 256, 0, stream>>>(xnb, emb_bf, nullptr, out,
                                                   1024, 32000, D_MODEL, 8);
}